// Round 1
// 330.144 us; speedup vs baseline: 1.0750x; 1.0750x over previous
//
#include <hip/hip_runtime.h>

#define NN 50000
#define NE 800000
#define F 128
#define EPS 1e-5f

typedef __attribute__((ext_vector_type(8))) short bf16x8;
typedef __attribute__((ext_vector_type(4))) float f32x4;

__device__ inline unsigned short f2bf_rn(float f) {
    unsigned u = __builtin_bit_cast(unsigned, f);
    u += 0x7fffu + ((u >> 16) & 1u);
    return (unsigned short)(u >> 16);
}
__device__ inline float bf2f(unsigned short h) {
    unsigned u = ((unsigned)h) << 16;
    return __builtin_bit_cast(float, u);
}

// ---------------- degree / CSR build ----------------

__global__ __launch_bounds__(256) void hist_k(const int* __restrict__ dst, int* __restrict__ deg, int E) {
    int base = (blockIdx.x * 256 + threadIdx.x) * 8;
    if (base >= E) return;
    int4 d0 = *(const int4*)&dst[base];
    int4 d1 = *(const int4*)&dst[base + 4];
    atomicAdd(&deg[d0.x], 1); atomicAdd(&deg[d0.y], 1);
    atomicAdd(&deg[d0.z], 1); atomicAdd(&deg[d0.w], 1);
    atomicAdd(&deg[d1.x], 1); atomicAdd(&deg[d1.y], 1);
    atomicAdd(&deg[d1.z], 1); atomicAdd(&deg[d1.w], 1);
}

__global__ __launch_bounds__(256) void block_sums_k(const int* __restrict__ deg, int* __restrict__ bsum, int N) {
    __shared__ int s[256];
    int t = threadIdx.x;
    int i = blockIdx.x * 256 + t;
    s[t] = (i < N) ? deg[i] : 0;
    __syncthreads();
    for (int off = 128; off > 0; off >>= 1) {
        if (t < off) s[t] += s[t + off];
        __syncthreads();
    }
    if (t == 0) bsum[blockIdx.x] = s[0];
}

__global__ __launch_bounds__(256) void scan_partials_k(const int* __restrict__ bsum, int* __restrict__ bpre, int nb) {
    __shared__ int s[256];
    int t = threadIdx.x;
    int v = (t < nb) ? bsum[t] : 0;
    s[t] = v;
    __syncthreads();
    for (int off = 1; off < 256; off <<= 1) {
        int add = (t >= off) ? s[t - off] : 0;
        __syncthreads();
        s[t] += add;
        __syncthreads();
    }
    if (t < nb) bpre[t] = s[t] - v;   // exclusive
}

__global__ __launch_bounds__(256) void scan_final_k(const int* __restrict__ deg, const int* __restrict__ bpre,
                                                    int* __restrict__ rp, int* __restrict__ fill,
                                                    float* __restrict__ dinv, int N, int E) {
    __shared__ int s[256];
    int t = threadIdx.x;
    int i = blockIdx.x * 256 + t;
    int v = (i < N) ? deg[i] : 0;
    s[t] = v;
    __syncthreads();
    for (int off = 1; off < 256; off <<= 1) {
        int add = (t >= off) ? s[t - off] : 0;
        __syncthreads();
        s[t] += add;
        __syncthreads();
    }
    int excl = s[t] - v + bpre[blockIdx.x];
    if (i < N) {
        rp[i] = excl;
        fill[i] = excl;
        dinv[i] = rsqrtf((float)v + 1.0f);
    }
    if (i == 0) rp[N] = E;
}

__global__ __launch_bounds__(256) void fill_k(const int* __restrict__ src, const int* __restrict__ dst,
                                              int* __restrict__ fill, int* __restrict__ col, int E) {
    int base = (blockIdx.x * 256 + threadIdx.x) * 8;
    if (base >= E) return;
    int4 d0 = *(const int4*)&dst[base];
    int4 d1 = *(const int4*)&dst[base + 4];
    int4 s0 = *(const int4*)&src[base];
    int4 s1 = *(const int4*)&src[base + 4];
    int p0 = atomicAdd(&fill[d0.x], 1);
    int p1 = atomicAdd(&fill[d0.y], 1);
    int p2 = atomicAdd(&fill[d0.z], 1);
    int p3 = atomicAdd(&fill[d0.w], 1);
    int p4 = atomicAdd(&fill[d1.x], 1);
    int p5 = atomicAdd(&fill[d1.y], 1);
    int p6 = atomicAdd(&fill[d1.z], 1);
    int p7 = atomicAdd(&fill[d1.w], 1);
    col[p0] = s0.x; col[p1] = s0.y; col[p2] = s0.z; col[p3] = s0.w;
    col[p4] = s1.x; col[p5] = s1.y; col[p6] = s1.z; col[p7] = s1.w;
}

// ---------------- W pre-pack into MFMA B-fragment order (bf16 hi/lo), all 4 layers ----------------
// frag map (16x16x32): lane l holds, for col-frag n / k-step s:
//   col = 16n + (l&15), k = 32s + 4*(l>>4) + j + 16h   (elem i = 4h + j)
// packed index: ((s*8 + n)*64 + l)*8 + i

__global__ __launch_bounds__(256) void pack_all_k(const float* __restrict__ W0, const float* __restrict__ W1,
                                                  const float* __restrict__ W2, const float* __restrict__ W3,
                                                  unsigned short* __restrict__ wh, unsigned short* __restrict__ wl) {
    int gidx = blockIdx.x * 256 + threadIdx.x;     // 0..65535
    int layer = gidx >> 14;
    int idx = gidx & 16383;
    const float* W = (layer == 0) ? W0 : (layer == 1) ? W1 : (layer == 2) ? W2 : W3;
    int i = idx & 7;
    int l = (idx >> 3) & 63;
    int n = (idx >> 9) & 7;
    int s = idx >> 12;
    int h = i >> 2, j = i & 3;
    int k = 32 * s + 4 * (l >> 4) + j + 16 * h;
    int c = 16 * n + (l & 15);
    float f = W[k * F + c];
    unsigned short hb = f2bf_rn(f);
    float rest = f - bf2f(hb);
    unsigned short lb = f2bf_rn(rest);
    wh[gidx] = hb;
    wl[gidx] = lb;
}

// ---------------- MFMA GEMM: Hb[M,128] = bf16((A[M,128] @ W) * dinv[row]) ----------------
// LDS-free: wave w owns rows 16w..16w+15 of a 64-row block tile, all 128 cols.
// A frags straight from global (each 64B line consumed by 4 lanes); B double-buffered
// one k-step ahead from L2. 3-term bf16 split: Ah*Wh + Al*Wh + Ah*Wl.

__global__ __launch_bounds__(256, 2) void gemm_mfma_k(const float* __restrict__ A,
                                                      const unsigned short* __restrict__ wh,
                                                      const unsigned short* __restrict__ wl,
                                                      const float* __restrict__ dinv,
                                                      unsigned short* __restrict__ Hb, int M) {
    const int tid = threadIdx.x;
    const int w = tid >> 6;
    const int l = tid & 63;
    const int lr = l & 15;
    const int g = l >> 4;
    const int row0 = blockIdx.x * 64;
    const int arow = min(row0 + w * 16 + lr, M - 1);
    const float* ap = A + (size_t)arow * F + g * 4;

    // issue all A loads (8 x dwordx4)
    float4 af[4][2];
#pragma unroll
    for (int s = 0; s < 4; ++s) {
        af[s][0] = *(const float4*)(ap + s * 32);
        af[s][1] = *(const float4*)(ap + s * 32 + 16);
    }

    const unsigned short* bh = wh + (size_t)l * 8;
    const unsigned short* bl = wl + (size_t)l * 8;
    bf16x8 Bh[2][8], Bl[2][8];
#pragma unroll
    for (int n = 0; n < 8; ++n) {
        Bh[0][n] = *(const bf16x8*)(bh + (size_t)n * 512);
        Bl[0][n] = *(const bf16x8*)(bl + (size_t)n * 512);
    }

    // convert A to hi/lo bf16 fragments
    bf16x8 ah[4], al[4];
#pragma unroll
    for (int s = 0; s < 4; ++s) {
#pragma unroll
        for (int i = 0; i < 8; ++i) {
            float f = (i < 4) ? (&af[s][0].x)[i] : (&af[s][1].x)[i - 4];
            unsigned short hb = f2bf_rn(f);
            ah[s][i] = (short)hb;
            al[s][i] = (short)f2bf_rn(f - bf2f(hb));
        }
    }

    f32x4 acc[8] = {};
#pragma unroll
    for (int s = 0; s < 4; ++s) {
        const int cur = s & 1, nxt = cur ^ 1;
        if (s < 3) {
#pragma unroll
            for (int n = 0; n < 8; ++n) {
                Bh[nxt][n] = *(const bf16x8*)(bh + (size_t)((s + 1) * 8 + n) * 512);
                Bl[nxt][n] = *(const bf16x8*)(bl + (size_t)((s + 1) * 8 + n) * 512);
            }
        }
#pragma unroll
        for (int n = 0; n < 8; ++n) {
            acc[n] = __builtin_amdgcn_mfma_f32_16x16x32_bf16(ah[s], Bh[cur][n], acc[n], 0, 0, 0);
            acc[n] = __builtin_amdgcn_mfma_f32_16x16x32_bf16(al[s], Bh[cur][n], acc[n], 0, 0, 0);
            acc[n] = __builtin_amdgcn_mfma_f32_16x16x32_bf16(ah[s], Bl[cur][n], acc[n], 0, 0, 0);
        }
    }

    // epilogue: C row = 16w + 4g + r, col = 16n + lr; scale by dinv[row], store bf16
    float di[4];
#pragma unroll
    for (int r = 0; r < 4; ++r) {
        int row = row0 + w * 16 + g * 4 + r;
        di[r] = (row < M) ? dinv[row] : 0.f;
    }
#pragma unroll
    for (int n = 0; n < 8; ++n) {
#pragma unroll
        for (int r = 0; r < 4; ++r) {
            int row = row0 + w * 16 + g * 4 + r;
            if (row < M) Hb[(size_t)row * F + n * 16 + lr] = f2bf_rn(acc[n][r] * di[r]);
        }
    }
}

// ---------------- aggregation + self-loop + bias + BN + ReLU ----------------
// Hb (bf16) pre-scaled by dinv[src]; out = dinv[row]*(sum_neighbors + Hb[row]) + b -> BN -> ReLU
// one wave per dst row, lane handles 2 features; edge loop unrolled x16.

__global__ __launch_bounds__(256) void agg_bn_k(const unsigned short* __restrict__ Hb, const int* __restrict__ rp,
                                                const int* __restrict__ col, const float* __restrict__ dinv,
                                                const float* __restrict__ b, const float* __restrict__ g,
                                                const float* __restrict__ be, const float* __restrict__ m,
                                                const float* __restrict__ v,
                                                float* __restrict__ out, int N) {
    int wid = threadIdx.x >> 6;
    int lane = threadIdx.x & 63;
    int row = blockIdx.x * 4 + wid;
    if (row >= N) return;

    int e0 = rp[row], e1 = rp[row + 1];
    float sx = 0.f, sy = 0.f;
    int e = e0;
    for (; e + 16 <= e1; e += 16) {
        int c[16];
#pragma unroll
        for (int j = 0; j < 16; ++j) c[j] = col[e + j];
        unsigned hv[16];
#pragma unroll
        for (int j = 0; j < 16; ++j) hv[j] = *(const unsigned*)&Hb[(size_t)c[j] * F + 2 * lane];
#pragma unroll
        for (int j = 0; j < 16; ++j) {
            sx += bf2f((unsigned short)(hv[j] & 0xffffu));
            sy += bf2f((unsigned short)(hv[j] >> 16));
        }
    }
    for (; e + 4 <= e1; e += 4) {
        int c[4];
#pragma unroll
        for (int j = 0; j < 4; ++j) c[j] = col[e + j];
        unsigned hv[4];
#pragma unroll
        for (int j = 0; j < 4; ++j) hv[j] = *(const unsigned*)&Hb[(size_t)c[j] * F + 2 * lane];
#pragma unroll
        for (int j = 0; j < 4; ++j) {
            sx += bf2f((unsigned short)(hv[j] & 0xffffu));
            sy += bf2f((unsigned short)(hv[j] >> 16));
        }
    }
    for (; e < e1; ++e) {
        unsigned hv = *(const unsigned*)&Hb[(size_t)col[e] * F + 2 * lane];
        sx += bf2f((unsigned short)(hv & 0xffffu));
        sy += bf2f((unsigned short)(hv >> 16));
    }

    float di = dinv[row];
    unsigned hs = *(const unsigned*)&Hb[(size_t)row * F + 2 * lane];
    float hsx = bf2f((unsigned short)(hs & 0xffffu));
    float hsy = bf2f((unsigned short)(hs >> 16));
    int f0 = 2 * lane, f1 = f0 + 1;
    float rx = (sx + hsx) * di + b[f0];
    float ry = (sy + hsy) * di + b[f1];
    float ax = rsqrtf(v[f0] + EPS) * g[f0];
    float ay = rsqrtf(v[f1] + EPS) * g[f1];
    rx = fmaf(rx - m[f0], ax, be[f0]);
    ry = fmaf(ry - m[f1], ay, be[f1]);
    rx = fmaxf(rx, 0.f);
    ry = fmaxf(ry, 0.f);
    float2 o = {rx, ry};
    *(float2*)&out[(size_t)row * F + 2 * lane] = o;
}

// ---------------- final: out[N,10] = act @ w_out[128,10] + b_out ----------------
// 4 lanes per row (16 rows/wave, 64 rows/block). Lane q handles features
// [32q, 32q+32); w cached in LDS with q-stride 33 floats so the 4 quarters hit
// 4 distinct banks (stride-32 layout would be a 4-way conflict). Quad shfl_xor
// reduce, then the 4 lanes split the 10 stores (lane q stores classes q, q+4, q+8).

__global__ __launch_bounds__(256) void out_gemm_k(const float* __restrict__ act, const float* __restrict__ w,
                                                  const float* __restrict__ bo, float* __restrict__ out, int N) {
    __shared__ float wT[10 * 132];   // class c at wT[c*132 + q*33 + k], feature = 32q + k
    int t = threadIdx.x;
    for (int i = t; i < 1280; i += 256) {
        int c = i >> 7;
        int j = i & 127;                         // feature index
        wT[c * 132 + j + (j >> 5)] = w[j * 10 + c];
    }
    __syncthreads();

    int r = t >> 2;                               // row within block (0..63)
    int q = t & 3;                                // feature quarter
    int row = blockIdx.x * 64 + r;
    if (row >= N) return;

    const float* ap = act + (size_t)row * F + q * 32;
    float a[32];
#pragma unroll
    for (int i = 0; i < 8; ++i) {
        float4 v4 = *(const float4*)(ap + i * 4);
        a[i * 4 + 0] = v4.x; a[i * 4 + 1] = v4.y;
        a[i * 4 + 2] = v4.z; a[i * 4 + 3] = v4.w;
    }

    float acc[10];
#pragma unroll
    for (int c = 0; c < 10; ++c) {
        const float* wp = &wT[c * 132 + q * 33];
        float s = 0.f;
#pragma unroll
        for (int k = 0; k < 32; ++k) s = fmaf(a[k], wp[k], s);
        acc[c] = s;
    }

    // reduce across the 4 quad lanes (lanes 4r..4r+3 of the same wave)
#pragma unroll
    for (int c = 0; c < 10; ++c) {
        acc[c] += __shfl_xor(acc[c], 1, 64);
        acc[c] += __shfl_xor(acc[c], 2, 64);
        acc[c] += bo[c];
    }

#pragma unroll
    for (int c = q; c < 10; c += 4) out[(size_t)row * 10 + c] = acc[c];
}

// ---------------- launch ----------------

extern "C" void kernel_launch(void* const* d_in, const int* in_sizes, int n_in,
                              void* d_out, int out_size, void* d_ws, size_t ws_size,
                              hipStream_t stream) {
    const float* x = (const float*)d_in[0];
    const int* ei = (const int*)d_in[1];
    const int* src = ei;
    const int* dst = ei + NE;
    const float *W[4], *B[4], *G[4], *BE[4], *Mn[4], *V[4];
    for (int l = 0; l < 4; ++l) {
        W[l]  = (const float*)d_in[2 + 6 * l];
        B[l]  = (const float*)d_in[3 + 6 * l];
        G[l]  = (const float*)d_in[4 + 6 * l];
        BE[l] = (const float*)d_in[5 + 6 * l];
        Mn[l] = (const float*)d_in[6 + 6 * l];
        V[l]  = (const float*)d_in[7 + 6 * l];
    }
    const float* w_out = (const float*)d_in[26];
    const float* b_out = (const float*)d_in[27];
    float* out = (float*)d_out;

    char* ws = (char*)d_ws;
    size_t off = 0;
    auto alloc = [&](size_t bytes) {
        void* p = ws + off;
        off = (off + bytes + 255) & ~(size_t)255;
        return p;
    };
    int*   deg  = (int*)alloc(NN * 4);
    int*   rp   = (int*)alloc((NN + 1) * 4);
    int*   fill = (int*)alloc(NN * 4);
    int*   bsum = (int*)alloc(256 * 4);
    int*   bpre = (int*)alloc(256 * 4);
    float* dinv = (float*)alloc(NN * 4);
    int*   col  = (int*)alloc((size_t)NE * 4);
    unsigned short* hb = (unsigned short*)alloc((size_t)NN * F * 2);
    float* act  = (float*)alloc((size_t)NN * F * 4);
    unsigned short* whp = (unsigned short*)alloc(4 * 16384 * 2);
    unsigned short* wlp = (unsigned short*)alloc(4 * 16384 * 2);

    hipMemsetAsync(deg, 0, NN * 4, stream);
    hist_k<<<(NE / 8 + 255) / 256, 256, 0, stream>>>(dst, deg, NE);
    block_sums_k<<<(NN + 255) / 256, 256, 0, stream>>>(deg, bsum, NN);
    scan_partials_k<<<1, 256, 0, stream>>>(bsum, bpre, (NN + 255) / 256);
    scan_final_k<<<(NN + 255) / 256, 256, 0, stream>>>(deg, bpre, rp, fill, dinv, NN, NE);
    fill_k<<<(NE / 8 + 255) / 256, 256, 0, stream>>>(src, dst, fill, col, NE);
    pack_all_k<<<256, 256, 0, stream>>>(W[0], W[1], W[2], W[3], whp, wlp);

    const float* cur = x;
    for (int l = 0; l < 4; ++l) {
        gemm_mfma_k<<<(NN + 63) / 64, 256, 0, stream>>>(cur, whp + l * 16384, wlp + l * 16384, dinv, hb, NN);
        agg_bn_k<<<(NN + 3) / 4, 256, 0, stream>>>(hb, rp, col, dinv, B[l], G[l], BE[l], Mn[l], V[l], act, NN);
        cur = act;
    }
    out_gemm_k<<<(NN + 63) / 64, 256, 0, stream>>>(act, w_out, b_out, out, NN);
}

// Round 2
// 324.085 us; speedup vs baseline: 1.0951x; 1.0187x over previous
//
#include <hip/hip_runtime.h>

#define NN 50000
#define NE 800000
#define F 128
#define EPS 1e-5f

typedef __attribute__((ext_vector_type(8))) short bf16x8;
typedef __attribute__((ext_vector_type(4))) float f32x4;

__device__ inline unsigned short f2bf_rn(float f) {
    unsigned u = __builtin_bit_cast(unsigned, f);
    u += 0x7fffu + ((u >> 16) & 1u);
    return (unsigned short)(u >> 16);
}
__device__ inline float bf2f(unsigned short h) {
    unsigned u = ((unsigned)h) << 16;
    return __builtin_bit_cast(float, u);
}

// ---------------- degree / CSR build (8-way XCD-privatized) ----------------
// group = blockIdx&7 matches the default round-robin block->XCD dispatch, so each
// deg8/fillcur copy's cache lines are touched by (mostly) one XCD's L2 -> no
// cross-XCD line bouncing on the atomics.

__global__ __launch_bounds__(256) void hist_k(const int* __restrict__ dst, int* __restrict__ deg8, int E) {
    int base = (blockIdx.x * 256 + threadIdx.x) * 8;
    if (base >= E) return;
    int* dg = deg8 + (blockIdx.x & 7) * NN;
    int4 d0 = *(const int4*)&dst[base];
    int4 d1 = *(const int4*)&dst[base + 4];
    atomicAdd(&dg[d0.x], 1); atomicAdd(&dg[d0.y], 1);
    atomicAdd(&dg[d0.z], 1); atomicAdd(&dg[d0.w], 1);
    atomicAdd(&dg[d1.x], 1); atomicAdd(&dg[d1.y], 1);
    atomicAdd(&dg[d1.z], 1); atomicAdd(&dg[d1.w], 1);
}

__global__ __launch_bounds__(256) void block_sums_k(const int* __restrict__ deg8, int* __restrict__ bsum, int N) {
    __shared__ int s[256];
    int t = threadIdx.x;
    int i = blockIdx.x * 256 + t;
    int v = 0;
    if (i < N) {
#pragma unroll
        for (int g = 0; g < 8; ++g) v += deg8[g * NN + i];
    }
    s[t] = v;
    __syncthreads();
    for (int off = 128; off > 0; off >>= 1) {
        if (t < off) s[t] += s[t + off];
        __syncthreads();
    }
    if (t == 0) bsum[blockIdx.x] = s[0];
}

__global__ __launch_bounds__(256) void scan_partials_k(const int* __restrict__ bsum, int* __restrict__ bpre, int nb) {
    __shared__ int s[256];
    int t = threadIdx.x;
    int v = (t < nb) ? bsum[t] : 0;
    s[t] = v;
    __syncthreads();
    for (int off = 1; off < 256; off <<= 1) {
        int add = (t >= off) ? s[t - off] : 0;
        __syncthreads();
        s[t] += add;
        __syncthreads();
    }
    if (t < nb) bpre[t] = s[t] - v;   // exclusive
}

__global__ __launch_bounds__(256) void scan_final_k(const int* __restrict__ deg8, const int* __restrict__ bpre,
                                                    int* __restrict__ rp, int* __restrict__ fillcur,
                                                    float* __restrict__ dinv, int N, int E) {
    __shared__ int s[256];
    int t = threadIdx.x;
    int i = blockIdx.x * 256 + t;
    int c[8];
    int v = 0;
#pragma unroll
    for (int g = 0; g < 8; ++g) {
        c[g] = (i < N) ? deg8[g * NN + i] : 0;
        v += c[g];
    }
    s[t] = v;
    __syncthreads();
    for (int off = 1; off < 256; off <<= 1) {
        int add = (t >= off) ? s[t - off] : 0;
        __syncthreads();
        s[t] += add;
        __syncthreads();
    }
    int excl = s[t] - v + bpre[blockIdx.x];
    if (i < N) {
        rp[i] = excl;
        int run = excl;
#pragma unroll
        for (int g = 0; g < 8; ++g) {
            fillcur[g * NN + i] = run;   // per-group cursor start
            run += c[g];
        }
        dinv[i] = rsqrtf((float)v + 1.0f);
    }
    if (i == 0) rp[N] = E;
}

__global__ __launch_bounds__(256) void fill_k(const int* __restrict__ src, const int* __restrict__ dst,
                                              int* __restrict__ fillcur, int* __restrict__ col, int E) {
    int base = (blockIdx.x * 256 + threadIdx.x) * 8;
    if (base >= E) return;
    int* fc = fillcur + (blockIdx.x & 7) * NN;  // same edge->group map as hist_k
    int4 d0 = *(const int4*)&dst[base];
    int4 d1 = *(const int4*)&dst[base + 4];
    int4 s0 = *(const int4*)&src[base];
    int4 s1 = *(const int4*)&src[base + 4];
    int p0 = atomicAdd(&fc[d0.x], 1);
    int p1 = atomicAdd(&fc[d0.y], 1);
    int p2 = atomicAdd(&fc[d0.z], 1);
    int p3 = atomicAdd(&fc[d0.w], 1);
    int p4 = atomicAdd(&fc[d1.x], 1);
    int p5 = atomicAdd(&fc[d1.y], 1);
    int p6 = atomicAdd(&fc[d1.z], 1);
    int p7 = atomicAdd(&fc[d1.w], 1);
    col[p0] = s0.x; col[p1] = s0.y; col[p2] = s0.z; col[p3] = s0.w;
    col[p4] = s1.x; col[p5] = s1.y; col[p6] = s1.z; col[p7] = s1.w;
}

// ---------------- W pre-pack into MFMA B-fragment order (bf16 hi/lo), all 4 layers ----------------
// frag map (16x16x32): lane l holds, for col-frag n / k-step s:
//   col = 16n + (l&15), k = 32s + 4*(l>>4) + j + 16h   (elem i = 4h + j)
// packed index: ((s*8 + n)*64 + l)*8 + i

__global__ __launch_bounds__(256) void pack_all_k(const float* __restrict__ W0, const float* __restrict__ W1,
                                                  const float* __restrict__ W2, const float* __restrict__ W3,
                                                  unsigned short* __restrict__ wh, unsigned short* __restrict__ wl) {
    int gidx = blockIdx.x * 256 + threadIdx.x;     // 0..65535
    int layer = gidx >> 14;
    int idx = gidx & 16383;
    const float* W = (layer == 0) ? W0 : (layer == 1) ? W1 : (layer == 2) ? W2 : W3;
    int i = idx & 7;
    int l = (idx >> 3) & 63;
    int n = (idx >> 9) & 7;
    int s = idx >> 12;
    int h = i >> 2, j = i & 3;
    int k = 32 * s + 4 * (l >> 4) + j + 16 * h;
    int c = 16 * n + (l & 15);
    float f = W[k * F + c];
    unsigned short hb = f2bf_rn(f);
    float rest = f - bf2f(hb);
    unsigned short lb = f2bf_rn(rest);
    wh[gidx] = hb;
    wl[gidx] = lb;
}

// ---------------- MFMA GEMM: Hb[M,128] = bf16((A[M,128] @ W) * dinv[row]) ----------------
// LDS-free: wave w owns rows 16w..16w+15 of a 64-row block tile, all 128 cols.
// A frags straight from global (each 64B line consumed by 4 lanes); B double-buffered
// one k-step ahead from L2. 3-term bf16 split: Ah*Wh + Al*Wh + Ah*Wl.

__global__ __launch_bounds__(256, 2) void gemm_mfma_k(const float* __restrict__ A,
                                                      const unsigned short* __restrict__ wh,
                                                      const unsigned short* __restrict__ wl,
                                                      const float* __restrict__ dinv,
                                                      unsigned short* __restrict__ Hb, int M) {
    const int tid = threadIdx.x;
    const int w = tid >> 6;
    const int l = tid & 63;
    const int lr = l & 15;
    const int g = l >> 4;
    const int row0 = blockIdx.x * 64;
    const int arow = min(row0 + w * 16 + lr, M - 1);
    const float* ap = A + (size_t)arow * F + g * 4;

    // issue all A loads (8 x dwordx4)
    float4 af[4][2];
#pragma unroll
    for (int s = 0; s < 4; ++s) {
        af[s][0] = *(const float4*)(ap + s * 32);
        af[s][1] = *(const float4*)(ap + s * 32 + 16);
    }

    const unsigned short* bh = wh + (size_t)l * 8;
    const unsigned short* bl = wl + (size_t)l * 8;
    bf16x8 Bh[2][8], Bl[2][8];
#pragma unroll
    for (int n = 0; n < 8; ++n) {
        Bh[0][n] = *(const bf16x8*)(bh + (size_t)n * 512);
        Bl[0][n] = *(const bf16x8*)(bl + (size_t)n * 512);
    }

    // convert A to hi/lo bf16 fragments
    bf16x8 ah[4], al[4];
#pragma unroll
    for (int s = 0; s < 4; ++s) {
#pragma unroll
        for (int i = 0; i < 8; ++i) {
            float f = (i < 4) ? (&af[s][0].x)[i] : (&af[s][1].x)[i - 4];
            unsigned short hb = f2bf_rn(f);
            ah[s][i] = (short)hb;
            al[s][i] = (short)f2bf_rn(f - bf2f(hb));
        }
    }

    f32x4 acc[8] = {};
#pragma unroll
    for (int s = 0; s < 4; ++s) {
        const int cur = s & 1, nxt = cur ^ 1;
        if (s < 3) {
#pragma unroll
            for (int n = 0; n < 8; ++n) {
                Bh[nxt][n] = *(const bf16x8*)(bh + (size_t)((s + 1) * 8 + n) * 512);
                Bl[nxt][n] = *(const bf16x8*)(bl + (size_t)((s + 1) * 8 + n) * 512);
            }
        }
#pragma unroll
        for (int n = 0; n < 8; ++n) {
            acc[n] = __builtin_amdgcn_mfma_f32_16x16x32_bf16(ah[s], Bh[cur][n], acc[n], 0, 0, 0);
            acc[n] = __builtin_amdgcn_mfma_f32_16x16x32_bf16(al[s], Bh[cur][n], acc[n], 0, 0, 0);
            acc[n] = __builtin_amdgcn_mfma_f32_16x16x32_bf16(ah[s], Bl[cur][n], acc[n], 0, 0, 0);
        }
    }

    // epilogue: C row = 16w + 4g + r, col = 16n + lr; scale by dinv[row], store bf16
    float di[4];
#pragma unroll
    for (int r = 0; r < 4; ++r) {
        int row = row0 + w * 16 + g * 4 + r;
        di[r] = (row < M) ? dinv[row] : 0.f;
    }
#pragma unroll
    for (int n = 0; n < 8; ++n) {
#pragma unroll
        for (int r = 0; r < 4; ++r) {
            int row = row0 + w * 16 + g * 4 + r;
            if (row < M) Hb[(size_t)row * F + n * 16 + lr] = f2bf_rn(acc[n][r] * di[r]);
        }
    }
}

// ---------------- aggregation + self-loop + bias + BN + ReLU ----------------
// Hb (bf16) pre-scaled by dinv[src]; out = dinv[row]*(sum_neighbors + Hb[row]) + b -> BN -> ReLU
// one wave per dst row, lane handles 2 features; edge loop unrolled x16.

__global__ __launch_bounds__(256) void agg_bn_k(const unsigned short* __restrict__ Hb, const int* __restrict__ rp,
                                                const int* __restrict__ col, const float* __restrict__ dinv,
                                                const float* __restrict__ b, const float* __restrict__ g,
                                                const float* __restrict__ be, const float* __restrict__ m,
                                                const float* __restrict__ v,
                                                float* __restrict__ out, int N) {
    int wid = threadIdx.x >> 6;
    int lane = threadIdx.x & 63;
    int row = blockIdx.x * 4 + wid;
    if (row >= N) return;

    int e0 = rp[row], e1 = rp[row + 1];
    float sx = 0.f, sy = 0.f;
    int e = e0;
    for (; e + 16 <= e1; e += 16) {
        int c[16];
#pragma unroll
        for (int j = 0; j < 16; ++j) c[j] = col[e + j];
        unsigned hv[16];
#pragma unroll
        for (int j = 0; j < 16; ++j) hv[j] = *(const unsigned*)&Hb[(size_t)c[j] * F + 2 * lane];
#pragma unroll
        for (int j = 0; j < 16; ++j) {
            sx += bf2f((unsigned short)(hv[j] & 0xffffu));
            sy += bf2f((unsigned short)(hv[j] >> 16));
        }
    }
    for (; e + 4 <= e1; e += 4) {
        int c[4];
#pragma unroll
        for (int j = 0; j < 4; ++j) c[j] = col[e + j];
        unsigned hv[4];
#pragma unroll
        for (int j = 0; j < 4; ++j) hv[j] = *(const unsigned*)&Hb[(size_t)c[j] * F + 2 * lane];
#pragma unroll
        for (int j = 0; j < 4; ++j) {
            sx += bf2f((unsigned short)(hv[j] & 0xffffu));
            sy += bf2f((unsigned short)(hv[j] >> 16));
        }
    }
    for (; e < e1; ++e) {
        unsigned hv = *(const unsigned*)&Hb[(size_t)col[e] * F + 2 * lane];
        sx += bf2f((unsigned short)(hv & 0xffffu));
        sy += bf2f((unsigned short)(hv >> 16));
    }

    float di = dinv[row];
    unsigned hs = *(const unsigned*)&Hb[(size_t)row * F + 2 * lane];
    float hsx = bf2f((unsigned short)(hs & 0xffffu));
    float hsy = bf2f((unsigned short)(hs >> 16));
    int f0 = 2 * lane, f1 = f0 + 1;
    float rx = (sx + hsx) * di + b[f0];
    float ry = (sy + hsy) * di + b[f1];
    float ax = rsqrtf(v[f0] + EPS) * g[f0];
    float ay = rsqrtf(v[f1] + EPS) * g[f1];
    rx = fmaf(rx - m[f0], ax, be[f0]);
    ry = fmaf(ry - m[f1], ay, be[f1]);
    rx = fmaxf(rx, 0.f);
    ry = fmaxf(ry, 0.f);
    float2 o = {rx, ry};
    *(float2*)&out[(size_t)row * F + 2 * lane] = o;
}

// ---------------- final: out[N,10] = act @ w_out[128,10] + b_out ----------------
// 4 lanes per row (16 rows/wave, 64 rows/block). Lane q handles features
// [32q, 32q+32); w cached in LDS with q-stride 33 floats so the 4 quarters hit
// 4 distinct banks (stride-32 layout would be a 4-way conflict). Quad shfl_xor
// reduce, then the 4 lanes split the 10 stores (lane q stores classes q, q+4, q+8).

__global__ __launch_bounds__(256) void out_gemm_k(const float* __restrict__ act, const float* __restrict__ w,
                                                  const float* __restrict__ bo, float* __restrict__ out, int N) {
    __shared__ float wT[10 * 132];   // class c at wT[c*132 + q*33 + k], feature = 32q + k
    int t = threadIdx.x;
    for (int i = t; i < 1280; i += 256) {
        int c = i >> 7;
        int j = i & 127;                         // feature index
        wT[c * 132 + j + (j >> 5)] = w[j * 10 + c];
    }
    __syncthreads();

    int r = t >> 2;                               // row within block (0..63)
    int q = t & 3;                                // feature quarter
    int row = blockIdx.x * 64 + r;
    if (row >= N) return;

    const float* ap = act + (size_t)row * F + q * 32;
    float a[32];
#pragma unroll
    for (int i = 0; i < 8; ++i) {
        float4 v4 = *(const float4*)(ap + i * 4);
        a[i * 4 + 0] = v4.x; a[i * 4 + 1] = v4.y;
        a[i * 4 + 2] = v4.z; a[i * 4 + 3] = v4.w;
    }

    float acc[10];
#pragma unroll
    for (int c = 0; c < 10; ++c) {
        const float* wp = &wT[c * 132 + q * 33];
        float s = 0.f;
#pragma unroll
        for (int k = 0; k < 32; ++k) s = fmaf(a[k], wp[k], s);
        acc[c] = s;
    }

    // reduce across the 4 quad lanes (lanes 4r..4r+3 of the same wave)
#pragma unroll
    for (int c = 0; c < 10; ++c) {
        acc[c] += __shfl_xor(acc[c], 1, 64);
        acc[c] += __shfl_xor(acc[c], 2, 64);
        acc[c] += bo[c];
    }

#pragma unroll
    for (int c = q; c < 10; c += 4) out[(size_t)row * 10 + c] = acc[c];
}

// ---------------- launch ----------------

extern "C" void kernel_launch(void* const* d_in, const int* in_sizes, int n_in,
                              void* d_out, int out_size, void* d_ws, size_t ws_size,
                              hipStream_t stream) {
    const float* x = (const float*)d_in[0];
    const int* ei = (const int*)d_in[1];
    const int* src = ei;
    const int* dst = ei + NE;
    const float *W[4], *B[4], *G[4], *BE[4], *Mn[4], *V[4];
    for (int l = 0; l < 4; ++l) {
        W[l]  = (const float*)d_in[2 + 6 * l];
        B[l]  = (const float*)d_in[3 + 6 * l];
        G[l]  = (const float*)d_in[4 + 6 * l];
        BE[l] = (const float*)d_in[5 + 6 * l];
        Mn[l] = (const float*)d_in[6 + 6 * l];
        V[l]  = (const float*)d_in[7 + 6 * l];
    }
    const float* w_out = (const float*)d_in[26];
    const float* b_out = (const float*)d_in[27];
    float* out = (float*)d_out;

    char* ws = (char*)d_ws;
    size_t off = 0;
    auto alloc = [&](size_t bytes) {
        void* p = ws + off;
        off = (off + bytes + 255) & ~(size_t)255;
        return p;
    };
    int*   deg8 = (int*)alloc((size_t)8 * NN * 4);
    int*   rp   = (int*)alloc((NN + 1) * 4);
    int*   fillc= (int*)alloc((size_t)8 * NN * 4);
    int*   bsum = (int*)alloc(256 * 4);
    int*   bpre = (int*)alloc(256 * 4);
    float* dinv = (float*)alloc(NN * 4);
    int*   col  = (int*)alloc((size_t)NE * 4);
    unsigned short* hb = (unsigned short*)alloc((size_t)NN * F * 2);
    float* act  = (float*)alloc((size_t)NN * F * 4);
    unsigned short* whp = (unsigned short*)alloc(4 * 16384 * 2);
    unsigned short* wlp = (unsigned short*)alloc(4 * 16384 * 2);

    hipMemsetAsync(deg8, 0, (size_t)8 * NN * 4, stream);
    hist_k<<<(NE / 8 + 255) / 256, 256, 0, stream>>>(dst, deg8, NE);
    block_sums_k<<<(NN + 255) / 256, 256, 0, stream>>>(deg8, bsum, NN);
    scan_partials_k<<<1, 256, 0, stream>>>(bsum, bpre, (NN + 255) / 256);
    scan_final_k<<<(NN + 255) / 256, 256, 0, stream>>>(deg8, bpre, rp, fillc, dinv, NN, NE);
    fill_k<<<(NE / 8 + 255) / 256, 256, 0, stream>>>(src, dst, fillc, col, NE);
    pack_all_k<<<256, 256, 0, stream>>>(W[0], W[1], W[2], W[3], whp, wlp);

    const float* cur = x;
    for (int l = 0; l < 4; ++l) {
        gemm_mfma_k<<<(NN + 63) / 64, 256, 0, stream>>>(cur, whp + l * 16384, wlp + l * 16384, dinv, hb, NN);
        agg_bn_k<<<(NN + 3) / 4, 256, 0, stream>>>(hb, rp, col, dinv, B[l], G[l], BE[l], Mn[l], V[l], act, NN);
        cur = act;
    }
    out_gemm_k<<<(NN + 63) / 64, 256, 0, stream>>>(act, w_out, b_out, out, NN);
}